// Round 4
// baseline (5711.047 us; speedup 1.0000x reference)
//
#include <hip/hip_runtime.h>

typedef unsigned short u16;
typedef short bf16x8 __attribute__((ext_vector_type(8)));
typedef float f32x4 __attribute__((ext_vector_type(4)));
typedef u16 u16x8 __attribute__((ext_vector_type(8)));

#define SLABH 262144  // h-hi slab elems (256*1024)

__device__ inline u16 f2bf(float f) {
  unsigned u = __float_as_uint(f);
  return (u16)((u + 0x7fffu + ((u >> 16) & 1u)) >> 16);
}
__device__ inline float bf2f(u16 h) { return __uint_as_float(((unsigned)h) << 16); }
__device__ inline float sigf(float x) { return 1.f / (1.f + __expf(-x)); }
__device__ inline float tanh_fast(float x) { return 1.f - 2.f / (__expf(2.f * x) + 1.f); }
// interleaved weight-row R -> original gate-major row (gate in bits 3-4)
__device__ inline int origR2(int R) { return ((R >> 3) & 3) * 1024 + (R >> 5) * 8 + (R & 7); }

__device__ inline void gload_lds16(const u16* g, u16* l) {
  __builtin_amdgcn_global_load_lds(
      (const __attribute__((address_space(1))) void*)g,
      (__attribute__((address_space(3))) void*)l, 16, 0, 0);
}

__device__ __forceinline__ void gbar() { __builtin_amdgcn_s_barrier(); }

template <int N>
__device__ __forceinline__ void waitv() {
  if constexpr (N == 0) asm volatile("s_waitcnt vmcnt(0)" ::: "memory");
  else if constexpr (N == 5) asm volatile("s_waitcnt vmcnt(5)" ::: "memory");
  else if constexpr (N == 6) asm volatile("s_waitcnt vmcnt(6)" ::: "memory");
  else if constexpr (N == 10) asm volatile("s_waitcnt vmcnt(10)" ::: "memory");
  else if constexpr (N == 12) asm volatile("s_waitcnt vmcnt(12)" ::: "memory");
}

// logical 1024-K-block -> (A plane, B plane)
// MODE 0: bf16x3 of [Ahi|Alo] x [Bhi|Blo]: (0,0) (1,0) (0,1)
// MODE 1: step0 6 blocks over x,h and Wih,Whh planes
// MODE 2: plain bf16 hi-only
template <int MODE>
__device__ __forceinline__ void kmap(int kblk, int& ka, int& kb) {
  if constexpr (MODE == 0) { ka = kblk & 1; kb = kblk >> 1; }
  else if constexpr (MODE == 1) {
    int hi = (kblk >= 3) ? 2 : 0;
    int k3 = kblk - ((kblk >= 3) ? 3 : 0);
    ka = hi + (k3 == 1);
    kb = hi + (k3 == 2);
  } else { ka = 0; kb = 0; }
}

// C[m][n] = sum over logical K (NT*64) of A[m][.]*B[n][.], planes pitch 1024.
// BM=128, BN 32/64, BK=64, 256 thr / 4 waves. Depth-3 prefetch, 4 LDS bufs,
// race-safe order: wait vmcnt -> barrier -> STAGE(t+3) -> COMPUTE(t).
// XOR-swizzle on global source + ds_read (linear LDS dest).
// EPI: 0 = f32 store, 1 = fused LSTM cell (BN=32), 2 = f32 + bias store.
template <int NT, int MODE, int BN, int NBC, int EPI, int SWZ>
__global__ __launch_bounds__(256) void gemmk(
    const u16* __restrict__ A0p, const u16* __restrict__ A1p,
    const u16* __restrict__ A2p, const u16* __restrict__ A3p,
    const u16* __restrict__ B0p, const u16* __restrict__ B1p,
    const u16* __restrict__ B2p, const u16* __restrict__ B3p,
    const float* __restrict__ bias, float* __restrict__ cbuf,
    u16* __restrict__ hhi, u16* __restrict__ hlo, float* __restrict__ fout) {
  constexpr int ROWS = 128 + BN;
  constexpr int TSE = ROWS * 64;      // elems per LDS buffer
  constexpr int UNITS = ROWS / 32;    // 16B units per thread per stage (5 or 6)
  constexpr int NA = BN / 32;         // n-frags per wave

  __shared__ __attribute__((aligned(16))) u16 ts[4 * TSE];

  const int bid = blockIdx.x, tid = threadIdx.x;
  int mb, nb;
  if constexpr (SWZ) {  // XCD x owns contiguous nb slice -> B slice L2-resident
    int x = bid & 7, i = bid >> 3;
    nb = x * (NBC / 8) + (i >> 1);
    mb = i & 1;
  } else {  // mb-major: consecutive bids share the A tile
    nb = bid % NBC;
    mb = bid / NBC;
  }

  const int lane = tid & 63, wid = tid >> 6;
  const int wrow = (wid >> 1) * 64;
  const int wcol = (wid & 1) * (BN / 2);
  const int lr = lane & 15, kq = lane >> 4;

  const size_t Aoff = (size_t)mb * 128 * 1024;
  const size_t Boff = (size_t)nb * BN * 1024;

  int uoff[UNITS];
#pragma unroll
  for (int u = 0; u < UNITS; u++) {
    int ui = u * 256 + tid;
    int r = ui >> 3, j = ui & 7;
    int jp = j ^ (r & 7);  // pre-swizzled source unit
    uoff[u] = (u < 4 ? r : r - 128) * 1024 + jp * 8;
  }

  f32x4 acc[4][NA];
#pragma unroll
  for (int m = 0; m < 4; m++)
#pragma unroll
    for (int n = 0; n < NA; n++) acc[m][n] = (f32x4)0.f;

  auto STAGE = [&](int buf, int kt) {
    int kblk = kt >> 4, ko = (kt & 15) * 64;
    int ka, kb;
    kmap<MODE>(kblk, ka, kb);
    const u16* ab = (ka == 0 ? A0p : ka == 1 ? A1p : ka == 2 ? A2p : A3p) + Aoff;
    const u16* bb = (kb == 0 ? B0p : kb == 1 ? B1p : kb == 2 ? B2p : B3p) + Boff;
    u16* lb = &ts[buf * TSE];
#pragma unroll
    for (int u = 0; u < UNITS; u++)
      gload_lds16((u < 4 ? ab : bb) + uoff[u] + ko, lb + (u * 256 + tid) * 8);
  };

  auto COMPUTE = [&](int cur) {
    const char* base = (const char*)&ts[cur * TSE];
    bf16x8 af[4][2], bv[NA][2];
#pragma unroll
    for (int m = 0; m < 4; m++)
#pragma unroll
      for (int kh = 0; kh < 2; kh++) {
        int row = wrow + m * 16 + lr;
        int sw = (kh * 4 + kq) ^ (row & 7);
        af[m][kh] = *(const bf16x8*)(base + row * 128 + sw * 16);
      }
#pragma unroll
    for (int n = 0; n < NA; n++)
#pragma unroll
      for (int kh = 0; kh < 2; kh++) {
        int row = 128 + wcol + n * 16 + lr;
        int sw = (kh * 4 + kq) ^ (row & 7);
        bv[n][kh] = *(const bf16x8*)(base + row * 128 + sw * 16);
      }
#pragma unroll
    for (int kh = 0; kh < 2; kh++)
#pragma unroll
      for (int m = 0; m < 4; m++)
#pragma unroll
        for (int n = 0; n < NA; n++)
          acc[m][n] = __builtin_amdgcn_mfma_f32_16x16x32_bf16(af[m][kh], bv[n][kh], acc[m][n], 0, 0, 0);
  };

  // depth-3 prologue
  STAGE(0, 0);
  STAGE(1, 1);
  STAGE(2, 2);
  for (int t = 0; t < NT - 3; t++) {
    waitv<2 * UNITS>();  // stage t complete (3 stages outstanding -> 2)
    gbar();              // all waves' stage-t loads landed; COMPUTE(t-1) done
    STAGE((t + 3) & 3, t + 3);  // overwrites buf (t-1)&3: safe after barrier
    COMPUTE(t & 3);
  }
  waitv<2 * UNITS>(); gbar(); COMPUTE((NT - 3) & 3);
  waitv<UNITS>();     gbar(); COMPUTE((NT - 2) & 3);
  waitv<0>();         gbar(); COMPUTE((NT - 1) & 3);

  if constexpr (EPI == 0 || EPI == 2) {
    float* Cb = fout + (size_t)(mb * 128 + wrow) * 1024 + nb * BN + wcol;
#pragma unroll
    for (int n = 0; n < NA; n++) {
      float bl = (EPI == 2) ? bias[nb * BN + wcol + n * 16 + lr] : 0.f;
#pragma unroll
      for (int m = 0; m < 4; m++)
#pragma unroll
        for (int j = 0; j < 4; j++)
          Cb[(size_t)(m * 16 + kq * 4 + j) * 1024 + n * 16 + lr] = acc[m][n][j] + bl;
    }
  } else {
    // fused LSTM cell (BN=32): block cols = R in [nb*32, nb*32+32):
    // gate = (c>>3)&3, orig col n = nb*8 + (c&7)
    float* g = (float*)ts;  // 128 x stride-36 exchange buffer (fits in ts)
    __syncthreads();
#pragma unroll
    for (int m = 0; m < 4; m++)
#pragma unroll
      for (int j = 0; j < 4; j++)
        g[(wrow + m * 16 + kq * 4 + j) * 36 + wcol + lr] = acc[m][0][j];
    __syncthreads();
    const int nn = tid & 7, rb = tid >> 3;
#pragma unroll
    for (int i = 0; i < 4; i++) {
      int r = rb + i * 32;
      float xi = g[r * 36 + nn] + bias[nb * 32 + nn];
      float xf = g[r * 36 + 8 + nn] + bias[nb * 32 + 8 + nn];
      float xg = g[r * 36 + 16 + nn] + bias[nb * 32 + 16 + nn];
      float xo = g[r * 36 + 24 + nn] + bias[nb * 32 + 24 + nn];
      int b = mb * 128 + r;
      int col = nb * 8 + nn;
      int cidx = b * 1024 + col;
      float cn = sigf(xf) * cbuf[cidx] + sigf(xi) * tanh_fast(xg);
      float h = sigf(xo) * tanh_fast(cn);
      cbuf[cidx] = cn;
      u16 hi = f2bf(h);
      u16 lo = f2bf(h - bf2f(hi));
      hhi[b * 1024 + col] = hi;
      hlo[b * 1024 + col] = lo;
    }
  }
}

// ---- prep kernels (all planes pitch 1024) ----

// split f32 rows into bf16 hi(/lo) planes; IMAP applies origR2 row gather
template <bool IMAP, bool WLO>
__global__ __launch_bounds__(256) void prep_split(const float* __restrict__ src,
                                                  u16* __restrict__ hi_p,
                                                  u16* __restrict__ lo_p) {
  int i = blockIdx.x * 256 + threadIdx.x;
  int r = i >> 7, k8 = (i & 127) << 3;
  int orig = IMAP ? origR2(r) : r;
  const float* s = src + (size_t)orig * 1024 + k8;
  u16x8 oh, ol;
#pragma unroll
  for (int e = 0; e < 8; e++) {
    float f = s[e];
    u16 h = f2bf(f);
    oh[e] = h;
    if constexpr (WLO) ol[e] = f2bf(f - bf2f(h));
  }
  *(u16x8*)&hi_p[(size_t)r * 1024 + k8] = oh;
  if constexpr (WLO) *(u16x8*)&lo_p[(size_t)r * 1024 + k8] = ol;
}

// Wlt[k][j] = W_lin[j][k] hi/lo planes (transpose, strided reads)
__global__ __launch_bounds__(256) void prep_wlt(const float* __restrict__ W,
                                                u16* __restrict__ hi_p,
                                                u16* __restrict__ lo_p) {
  int i = blockIdx.x * 256 + threadIdx.x;  // 1024 rows x 128 units
  int k = i >> 7, j8 = (i & 127) << 3;
  u16x8 oh, ol;
#pragma unroll
  for (int e = 0; e < 8; e++) {
    float f = W[(size_t)(j8 + e) * 1024 + k];
    u16 h = f2bf(f);
    oh[e] = h;
    ol[e] = f2bf(f - bf2f(h));
  }
  *(u16x8*)&hi_p[(size_t)k * 1024 + j8] = oh;
  *(u16x8*)&lo_p[(size_t)k * 1024 + j8] = ol;
}

// Beff[R] = split(Wc_f32[R] + W_hh[origR2(R)])
__global__ __launch_bounds__(256) void prep_beff(const float* __restrict__ Wc,
                                                 const float* __restrict__ Whh,
                                                 u16* __restrict__ hi_p,
                                                 u16* __restrict__ lo_p) {
  int i = blockIdx.x * 256 + threadIdx.x;
  int r = i >> 7, k8 = (i & 127) << 3;
  const float* s1 = Wc + (size_t)r * 1024 + k8;
  const float* s2 = Whh + (size_t)origR2(r) * 1024 + k8;
  u16x8 oh, ol;
#pragma unroll
  for (int e = 0; e < 8; e++) {
    float f = s1[e] + s2[e];
    u16 h = f2bf(f);
    oh[e] = h;
    ol[e] = f2bf(f - bf2f(h));
  }
  *(u16x8*)&hi_p[(size_t)r * 1024 + k8] = oh;
  *(u16x8*)&lo_p[(size_t)r * 1024 + k8] = ol;
}

// x0/h0 -> hi/lo planes; cbuf <- c0
__global__ __launch_bounds__(256) void prep_a0(const float* __restrict__ x0,
                                               const float* __restrict__ h0,
                                               const float* __restrict__ c0,
                                               u16* __restrict__ xhi, u16* __restrict__ xlo,
                                               u16* __restrict__ hhi, u16* __restrict__ hlo,
                                               float* __restrict__ cbuf) {
  int i = blockIdx.x * 256 + threadIdx.x;  // 65536
  int sel = i >> 15, ii = i & 32767;
  int r = ii >> 7, k8 = (ii & 127) << 3;
  const float* s = (sel ? h0 : x0) + r * 1024 + k8;
  u16* hp = (sel ? hhi : xhi) + r * 1024 + k8;
  u16* lp = (sel ? hlo : xlo) + r * 1024 + k8;
  u16x8 oh, ol;
#pragma unroll
  for (int e = 0; e < 8; e++) {
    float f = s[e];
    u16 h = f2bf(f);
    oh[e] = h;
    ol[e] = f2bf(f - bf2f(h));
  }
  *(u16x8*)hp = oh;
  *(u16x8*)lp = ol;
  if (i < 32768) {
    float4 v0 = *(const float4*)&c0[i * 8];
    float4 v1 = *(const float4*)&c0[i * 8 + 4];
    *(float4*)&cbuf[i * 8] = v0;
    *(float4*)&cbuf[i * 8 + 4] = v1;
  }
}

// bc0[R] = b_ih[o]+b_hh[o]; bc1[R] = bc0[R] + dot(W_ih[o,:], b_lin)
__global__ __launch_bounds__(256) void prep_bias(const float* __restrict__ Wih,
                                                 const float* __restrict__ b_ih,
                                                 const float* __restrict__ b_hh,
                                                 const float* __restrict__ b_lin,
                                                 float* __restrict__ bc0,
                                                 float* __restrict__ bc1) {
  int wid = threadIdx.x >> 6, lane = threadIdx.x & 63;
  int R = blockIdx.x * 4 + wid;
  int o = origR2(R);
  float p = 0.f;
#pragma unroll
  for (int it = 0; it < 16; it++) p += Wih[(size_t)o * 1024 + lane + it * 64] * b_lin[lane + it * 64];
#pragma unroll
  for (int m = 1; m < 64; m <<= 1) p += __shfl_xor(p, m);
  if (lane == 0) {
    float s = b_ih[o] + b_hh[o];
    bc0[R] = s;
    bc1[R] = s + p;
  }
}

// In-place BatchNorm over batch axis, 2-pass (sum + sumsq fused)
__global__ __launch_bounds__(256) void bn_kernel(float* __restrict__ out) {
  int t = blockIdx.x >> 2;
  int d = ((blockIdx.x & 3) << 8) + threadIdx.x;
  float* base = out + (size_t)t * (256 * 1024) + d;
  float s = 0.f, s2 = 0.f;
  for (int b = 0; b < 256; b++) {
    float v = base[b * 1024];
    s += v;
    s2 += v * v;
  }
  float mean = s * (1.f / 256.f);
  float var = fmaxf(s2 * (1.f / 256.f) - mean * mean, 0.f);
  float rstd = rsqrtf(var + 1e-5f);
  for (int b = 0; b < 256; b++) base[b * 1024] = (base[b * 1024] - mean) * rstd;
}

extern "C" void kernel_launch(void* const* d_in, const int* in_sizes, int n_in,
                              void* d_out, int out_size, void* d_ws, size_t ws_size,
                              hipStream_t stream) {
  const float* inputs = (const float*)d_in[0];
  const float* W_ih = (const float*)d_in[1];
  const float* W_hh = (const float*)d_in[2];
  const float* b_ih = (const float*)d_in[3];
  const float* b_hh = (const float*)d_in[4];
  const float* W_lin = (const float*)d_in[5];
  const float* b_lin = (const float*)d_in[6];
  const float* h0 = (const float*)d_in[7];
  const float* c0 = (const float*)d_in[8];
  float* out = (float*)d_out;

  char* ws = (char*)d_ws;
  float* bc0 = (float*)(ws + 0);             // 16,384
  float* bc1 = (float*)(ws + 16384);         // 16,384
  float* cbuf = (float*)(ws + 32768);        // 1,048,576
  u16* Wlin_hi = (u16*)(ws + 1081344);       // 2,097,152
  u16* Beff_hi = (u16*)(ws + 3178496);       // 8,388,608
  u16* Beff_lo = (u16*)(ws + 11567104);      // 8,388,608
  u16* xhi = (u16*)(ws + 19955712);          // 524,288
  u16* xlo = (u16*)(ws + 20480000);          // 524,288
  u16* h0hi = (u16*)(ws + 21004288);         // 524,288
  u16* h0lo = (u16*)(ws + 21528576);         // 524,288
  u16* Hlo0 = (u16*)(ws + 22052864);         // 524,288
  u16* Hlo1 = (u16*)(ws + 22577152);         // 524,288
  u16* Hhi = (u16*)(ws + 23101440);          // 67,108,864 (128 slabs of 512KB)
  // transients aliased inside Hhi (each dead before its slabs are written;
  // earliest aliased slab = 4, first overwritten by step t=4):
  u16* Whh_hi = (u16*)(ws + 23101440 + 2097152);    // slabs 4..19
  u16* Whh_lo = (u16*)(ws + 23101440 + 10485760);   // slabs 20..35
  u16* Wih_hi = (u16*)(ws + 23101440 + 18874368);   // slabs 36..51
  u16* Wih_lo = (u16*)(ws + 23101440 + 27262976);   // slabs 52..67
  u16* Wlt_hi = (u16*)(ws + 23101440 + 35651584);   // slabs 68..71
  u16* Wlt_lo = (u16*)(ws + 23101440 + 37748736);   // slabs 72..75
  float* Wc_f32 = (float*)(ws + 23101440 + 39845888);  // slabs 76..107

  prep_split<true, true><<<2048, 256, 0, stream>>>(W_ih, Wih_hi, Wih_lo);
  prep_split<true, true><<<2048, 256, 0, stream>>>(W_hh, Whh_hi, Whh_lo);
  prep_split<false, false><<<512, 256, 0, stream>>>(W_lin, Wlin_hi, nullptr);
  prep_wlt<<<512, 256, 0, stream>>>(W_lin, Wlt_hi, Wlt_lo);
  prep_a0<<<256, 256, 0, stream>>>(inputs, h0, c0, xhi, xlo, h0hi, h0lo, cbuf);
  prep_bias<<<1024, 256, 0, stream>>>(W_ih, b_ih, b_hh, b_lin, bc0, bc1);

  // W_c = W_ih @ W_lin (bf16x3), rows interleaved. M=4096, N=1024.
  gemmk<48, 0, 64, 16, 0, 0><<<512, 256, 0, stream>>>(
      Wih_hi, Wih_lo, nullptr, nullptr, Wlt_hi, Wlt_lo, nullptr, nullptr,
      nullptr, nullptr, nullptr, nullptr, Wc_f32);
  prep_beff<<<2048, 256, 0, stream>>>(Wc_f32, W_hh, Beff_hi, Beff_lo);

  // step 0: gates from (x0,h0), logical K=6144. N=4096, grid 256 (full chip).
  gemmk<96, 1, 32, 128, 1, 1><<<256, 256, 0, stream>>>(
      xhi, xlo, h0hi, h0lo, Wih_hi, Wih_lo, Whh_hi, Whh_lo,
      bc0, cbuf, Hhi, Hlo0, nullptr);
  // steps 1..127: gates from h only, logical K=3072 (bf16x3)
  for (int t = 1; t < 128; t++) {
    gemmk<48, 0, 32, 128, 1, 1><<<256, 256, 0, stream>>>(
        Hhi + (size_t)(t - 1) * SLABH, ((t - 1) & 1) ? Hlo1 : Hlo0, nullptr, nullptr,
        Beff_hi, Beff_lo, nullptr, nullptr,
        bc1, cbuf, Hhi + (size_t)t * SLABH, (t & 1) ? Hlo1 : Hlo0, nullptr);
  }

  // ys = Hs_hi @ W_lin_hi^T + b_lin (plain bf16; output only feeds BN).
  // M=32768, N=1024, mb-major for A-tile L2/L3 reuse.
  gemmk<16, 2, 64, 16, 2, 0><<<4096, 256, 0, stream>>>(
      Hhi, nullptr, nullptr, nullptr, Wlin_hi, nullptr, nullptr, nullptr,
      b_lin, nullptr, nullptr, nullptr, out);
  bn_kernel<<<512, 256, 0, stream>>>(out);
}

// Round 5
// 1535.465 us; speedup vs baseline: 3.7194x; 3.7194x over previous
//
#include <hip/hip_runtime.h>

typedef unsigned short u16;
typedef short bf16x8 __attribute__((ext_vector_type(8)));
typedef float f32x4 __attribute__((ext_vector_type(4)));
typedef u16 u16x8 __attribute__((ext_vector_type(8)));

#define SLABH 262144  // h-hi slab elems (256*1024)

__device__ inline u16 f2bf(float f) {
  unsigned u = __float_as_uint(f);
  return (u16)((u + 0x7fffu + ((u >> 16) & 1u)) >> 16);
}
__device__ inline float bf2f(u16 h) { return __uint_as_float(((unsigned)h) << 16); }
__device__ inline float sigf(float x) { return 1.f / (1.f + __expf(-x)); }
__device__ inline float tanh_fast(float x) { return 1.f - 2.f / (__expf(2.f * x) + 1.f); }
// interleaved weight-row R -> original gate-major row (gate in bits 3-4)
__device__ inline int origR2(int R) { return ((R >> 3) & 3) * 1024 + (R >> 5) * 8 + (R & 7); }

__device__ inline void gload_lds16(const u16* g, u16* l) {
  __builtin_amdgcn_global_load_lds(
      (const __attribute__((address_space(1))) void*)g,
      (__attribute__((address_space(3))) void*)l, 16, 0, 0);
}

__device__ __forceinline__ void gbar() { __builtin_amdgcn_s_barrier(); }

template <int N>
__device__ __forceinline__ void waitv() {
  if constexpr (N == 0) asm volatile("s_waitcnt vmcnt(0)" ::: "memory");
  else if constexpr (N == 8) asm volatile("s_waitcnt vmcnt(8)" ::: "memory");
  else if constexpr (N == 16) asm volatile("s_waitcnt vmcnt(16)" ::: "memory");
}

// C[m][n] = sum_k A[m][k]*B[n][k], planes pitch 1024, K = (MODE==1? NT/2 : NT)*64.
// MODE 0: bf16x3 joint staging: LDS rows [Ahi(BM)|Alo(BM)|Bhi(BN)|Blo(BN)],
//         combos hihi + lohi + hilo per K-chunk.
// MODE 1: like 0 but two K-phases with different plane sets (step 0: x then h).
// MODE 2: plain bf16 hi-only, LDS rows [A(BM)|B(BN)].
// All configs: 256 LDS rows x 64 k = 32 KB/buf, 4 bufs, depth-3 prefetch,
// 8 staging units/thread, XOR-swizzle on global source + ds_read addr.
// EPI: 0 = f32 store, 1 = fused LSTM cell (BM=BN=64), 2 = f32 + bias store.
// SWZ: 0 = nb=bid%NBW, 1 = step map (64nb x 4mb, XCD-sliced nb),
//      2 = y map (8nb x 256mb, XCD-sliced mb).
template <int BM, int BN, int NT, int MODE, int EPI, int SWZ, int NBW>
__global__ __launch_bounds__(256) void gemmk(
    const u16* __restrict__ A0p, const u16* __restrict__ A1p,
    const u16* __restrict__ A2p, const u16* __restrict__ A3p,
    const u16* __restrict__ B0p, const u16* __restrict__ B1p,
    const u16* __restrict__ B2p, const u16* __restrict__ B3p,
    const float* __restrict__ bias, float* __restrict__ cbuf,
    u16* __restrict__ hhi, u16* __restrict__ hlo, float* __restrict__ fout) {
  constexpr int TSE = 256 * 64;   // elems per LDS buffer (32 KB)
  constexpr int MR = BM / 32;     // m-frags per wave
  constexpr int NR = BN / 32;     // n-frags per wave

  __shared__ __attribute__((aligned(16))) u16 ts[4 * TSE];  // 128 KB

  const int bid = blockIdx.x, tid = threadIdx.x;
  int mb, nb;
  if constexpr (SWZ == 1) {        // steps: XCD owns 8-wide nb slice, all mb
    int x = bid & 7, i = bid >> 3;
    nb = x * 8 + (i & 7);
    mb = i >> 3;
  } else if constexpr (SWZ == 2) { // y: XCD owns 32-wide mb slice, all nb
    int x = bid & 7, i = bid >> 3;
    nb = i & 7;
    mb = x * 32 + (i >> 3);
  } else {
    nb = bid % NBW;
    mb = bid / NBW;
  }

  const int lane = tid & 63, wid = tid >> 6;
  const int wrow = (wid >> 1) * (BM / 2);
  const int wcol = (wid & 1) * (BN / 2);
  const int lr = lane & 15, kq = lane >> 4;

  const size_t Aoff = (size_t)mb * BM * 1024;
  const size_t Boff = (size_t)nb * BN * 1024;
  const int tid3 = tid >> 3;
  const int jp = (tid & 7) ^ (tid3 & 7);  // pre-swizzled source unit

  f32x4 acc[MR][NR];
#pragma unroll
  for (int m = 0; m < MR; m++)
#pragma unroll
    for (int n = 0; n < NR; n++) acc[m][n] = (f32x4)0.f;

  auto STAGE = [&](int buf, int kt) {
    const u16 *a0, *a1, *b0, *b1;
    int ko;
    if constexpr (MODE == 1) {
      if (kt >= NT / 2) { a0 = A2p; a1 = A3p; b0 = B2p; b1 = B3p; ko = (kt - NT / 2) * 64; }
      else { a0 = A0p; a1 = A1p; b0 = B0p; b1 = B1p; ko = kt * 64; }
    } else {
      a0 = A0p; a1 = A1p; b0 = B0p; b1 = B1p; ko = kt * 64;
    }
    u16* lb = &ts[buf * TSE];
#pragma unroll
    for (int u = 0; u < 8; u++) {
      const u16* src;
      int prow;
      if constexpr (MODE == 2) {  // sections: A rows [0,BM), B rows [BM,256)
        if (u < BM / 32) { src = a0 + Aoff; prow = u * 32 + tid3; }
        else { src = b0 + Boff; prow = (u - BM / 32) * 32 + tid3; }
      } else {  // sections of 64: Ahi, Alo, Bhi, Blo
        int s = u >> 1;
        src = (s == 0 ? a0 + Aoff : s == 1 ? a1 + Aoff : s == 2 ? b0 + Boff : b1 + Boff);
        prow = (u & 1) * 32 + tid3;
      }
      gload_lds16(src + prow * 1024 + jp * 8 + ko, lb + (u * 256 + tid) * 8);
    }
  };

  auto COMPUTE = [&](int cur) {
    const char* base = (const char*)&ts[cur * TSE];
    int sw0 = (lr & 7) * 16;
    if constexpr (MODE == 2) {
      bf16x8 a[MR][2], b[NR][2];
#pragma unroll
      for (int m = 0; m < MR; m++)
#pragma unroll
        for (int kh = 0; kh < 2; kh++) {
          int row = wrow + m * 16 + lr;
          a[m][kh] = *(const bf16x8*)(base + row * 128 + (((kh * 4 + kq) * 16) ^ sw0));
        }
#pragma unroll
      for (int n = 0; n < NR; n++)
#pragma unroll
        for (int kh = 0; kh < 2; kh++) {
          int row = BM + wcol + n * 16 + lr;
          b[n][kh] = *(const bf16x8*)(base + row * 128 + (((kh * 4 + kq) * 16) ^ sw0));
        }
#pragma unroll
      for (int kh = 0; kh < 2; kh++)
#pragma unroll
        for (int m = 0; m < MR; m++)
#pragma unroll
          for (int n = 0; n < NR; n++)
            acc[m][n] = __builtin_amdgcn_mfma_f32_16x16x32_bf16(a[m][kh], b[n][kh], acc[m][n], 0, 0, 0);
    } else {
      bf16x8 ah[2][2], al[2][2], bh[2][2], bl[2][2];
#pragma unroll
      for (int m = 0; m < 2; m++)
#pragma unroll
        for (int kh = 0; kh < 2; kh++) {
          int row = wrow + m * 16 + lr;
          int so = ((kh * 4 + kq) * 16) ^ sw0;
          ah[m][kh] = *(const bf16x8*)(base + row * 128 + so);
          al[m][kh] = *(const bf16x8*)(base + (row + 64) * 128 + so);
        }
#pragma unroll
      for (int n = 0; n < 2; n++)
#pragma unroll
        for (int kh = 0; kh < 2; kh++) {
          int row = 128 + wcol + n * 16 + lr;
          int so = ((kh * 4 + kq) * 16) ^ sw0;
          bh[n][kh] = *(const bf16x8*)(base + row * 128 + so);
          bl[n][kh] = *(const bf16x8*)(base + (row + 64) * 128 + so);
        }
#pragma unroll
      for (int kh = 0; kh < 2; kh++)
#pragma unroll
        for (int m = 0; m < 2; m++)
#pragma unroll
          for (int n = 0; n < 2; n++) {
            acc[m][n] = __builtin_amdgcn_mfma_f32_16x16x32_bf16(ah[m][kh], bh[n][kh], acc[m][n], 0, 0, 0);
            acc[m][n] = __builtin_amdgcn_mfma_f32_16x16x32_bf16(al[m][kh], bh[n][kh], acc[m][n], 0, 0, 0);
            acc[m][n] = __builtin_amdgcn_mfma_f32_16x16x32_bf16(ah[m][kh], bl[n][kh], acc[m][n], 0, 0, 0);
          }
    }
  };

  // depth-3, 4 buffers; order: wait -> barrier -> STAGE(t+3) -> COMPUTE(t)
  STAGE(0, 0);
  STAGE(1, 1);
  STAGE(2, 2);
  for (int t = 0; t < NT - 3; t++) {
    waitv<16>();
    gbar();
    STAGE((t + 3) & 3, t + 3);
    COMPUTE(t & 3);
  }
  waitv<16>(); gbar(); COMPUTE((NT - 3) & 3);
  waitv<8>();  gbar(); COMPUTE((NT - 2) & 3);
  waitv<0>();  gbar(); COMPUTE((NT - 1) & 3);

  if constexpr (EPI == 0 || EPI == 2) {
    float* Cb = fout + (size_t)(mb * BM + wrow) * 1024 + nb * BN + wcol;
#pragma unroll
    for (int n = 0; n < NR; n++) {
      float blv = (EPI == 2) ? bias[nb * BN + wcol + n * 16 + lr] : 0.f;
#pragma unroll
      for (int m = 0; m < MR; m++)
#pragma unroll
        for (int j = 0; j < 4; j++)
          Cb[(size_t)(m * 16 + kq * 4 + j) * 1024 + n * 16 + lr] = acc[m][n][j] + blv;
    }
  } else {
    // fused LSTM cell. Block tile: 64 batch rows x 64 interleaved R cols.
    // R = nb*64 + rr: gate = (rr>>3)&3, n = nb*16 + (rr>>5)*8 + (rr&7).
    float* g = (float*)ts;  // 64 x 65 f32 exchange
    __syncthreads();
#pragma unroll
    for (int m = 0; m < 2; m++)
#pragma unroll
      for (int n = 0; n < 2; n++)
#pragma unroll
        for (int j = 0; j < 4; j++)
          g[(wrow + m * 16 + kq * 4 + j) * 65 + wcol + n * 16 + lr] = acc[m][n][j];
    __syncthreads();
    const int n16 = tid & 15;          // local n index
    const int s = n16 & 7, q = n16 >> 3;
    const int cbase = q * 32 + s;      // col of gate i
    const float bi = bias[nb * 64 + cbase];
    const float bf = bias[nb * 64 + cbase + 8];
    const float bg = bias[nb * 64 + cbase + 16];
    const float bo = bias[nb * 64 + cbase + 24];
#pragma unroll
    for (int i = 0; i < 4; i++) {
      int br = (tid >> 4) + i * 16;    // local batch row
      float xi = g[br * 65 + cbase] + bi;
      float xf = g[br * 65 + cbase + 8] + bf;
      float xg = g[br * 65 + cbase + 16] + bg;
      float xo = g[br * 65 + cbase + 24] + bo;
      int b = mb * 64 + br;
      int col = nb * 16 + n16;
      int cidx = b * 1024 + col;
      float cn = sigf(xf) * cbuf[cidx] + sigf(xi) * tanh_fast(xg);
      float h = sigf(xo) * tanh_fast(cn);
      cbuf[cidx] = cn;
      u16 hi = f2bf(h);
      u16 lo = f2bf(h - bf2f(hi));
      hhi[cidx] = hi;
      hlo[cidx] = lo;
    }
  }
}

// ---- prep kernels (all planes pitch 1024) ----

template <bool IMAP, bool WLO>
__global__ __launch_bounds__(256) void prep_split(const float* __restrict__ src,
                                                  u16* __restrict__ hi_p,
                                                  u16* __restrict__ lo_p) {
  int i = blockIdx.x * 256 + threadIdx.x;
  int r = i >> 7, k8 = (i & 127) << 3;
  int orig = IMAP ? origR2(r) : r;
  const float* s = src + (size_t)orig * 1024 + k8;
  u16x8 oh, ol;
#pragma unroll
  for (int e = 0; e < 8; e++) {
    float f = s[e];
    u16 h = f2bf(f);
    oh[e] = h;
    if constexpr (WLO) ol[e] = f2bf(f - bf2f(h));
  }
  *(u16x8*)&hi_p[(size_t)r * 1024 + k8] = oh;
  if constexpr (WLO) *(u16x8*)&lo_p[(size_t)r * 1024 + k8] = ol;
}

__global__ __launch_bounds__(256) void prep_wlt(const float* __restrict__ W,
                                                u16* __restrict__ hi_p,
                                                u16* __restrict__ lo_p) {
  int i = blockIdx.x * 256 + threadIdx.x;  // 1024 rows x 128 units
  int k = i >> 7, j8 = (i & 127) << 3;
  u16x8 oh, ol;
#pragma unroll
  for (int e = 0; e < 8; e++) {
    float f = W[(size_t)(j8 + e) * 1024 + k];
    u16 h = f2bf(f);
    oh[e] = h;
    ol[e] = f2bf(f - bf2f(h));
  }
  *(u16x8*)&hi_p[(size_t)k * 1024 + j8] = oh;
  *(u16x8*)&lo_p[(size_t)k * 1024 + j8] = ol;
}

__global__ __launch_bounds__(256) void prep_beff(const float* __restrict__ Wc,
                                                 const float* __restrict__ Whh,
                                                 u16* __restrict__ hi_p,
                                                 u16* __restrict__ lo_p) {
  int i = blockIdx.x * 256 + threadIdx.x;
  int r = i >> 7, k8 = (i & 127) << 3;
  const float* s1 = Wc + (size_t)r * 1024 + k8;
  const float* s2 = Whh + (size_t)origR2(r) * 1024 + k8;
  u16x8 oh, ol;
#pragma unroll
  for (int e = 0; e < 8; e++) {
    float f = s1[e] + s2[e];
    u16 h = f2bf(f);
    oh[e] = h;
    ol[e] = f2bf(f - bf2f(h));
  }
  *(u16x8*)&hi_p[(size_t)r * 1024 + k8] = oh;
  *(u16x8*)&lo_p[(size_t)r * 1024 + k8] = ol;
}

__global__ __launch_bounds__(256) void prep_a0(const float* __restrict__ x0,
                                               const float* __restrict__ h0,
                                               const float* __restrict__ c0,
                                               u16* __restrict__ xhi, u16* __restrict__ xlo,
                                               u16* __restrict__ hhi, u16* __restrict__ hlo,
                                               float* __restrict__ cbuf) {
  int i = blockIdx.x * 256 + threadIdx.x;  // 65536
  int sel = i >> 15, ii = i & 32767;
  int r = ii >> 7, k8 = (ii & 127) << 3;
  const float* s = (sel ? h0 : x0) + r * 1024 + k8;
  u16* hp = (sel ? hhi : xhi) + r * 1024 + k8;
  u16* lp = (sel ? hlo : xlo) + r * 1024 + k8;
  u16x8 oh, ol;
#pragma unroll
  for (int e = 0; e < 8; e++) {
    float f = s[e];
    u16 h = f2bf(f);
    oh[e] = h;
    ol[e] = f2bf(f - bf2f(h));
  }
  *(u16x8*)hp = oh;
  *(u16x8*)lp = ol;
  if (i < 32768) {
    float4 v0 = *(const float4*)&c0[i * 8];
    float4 v1 = *(const float4*)&c0[i * 8 + 4];
    *(float4*)&cbuf[i * 8] = v0;
    *(float4*)&cbuf[i * 8 + 4] = v1;
  }
}

__global__ __launch_bounds__(256) void prep_bias(const float* __restrict__ Wih,
                                                 const float* __restrict__ b_ih,
                                                 const float* __restrict__ b_hh,
                                                 const float* __restrict__ b_lin,
                                                 float* __restrict__ bc0,
                                                 float* __restrict__ bc1) {
  int wid = threadIdx.x >> 6, lane = threadIdx.x & 63;
  int R = blockIdx.x * 4 + wid;
  int o = origR2(R);
  float p = 0.f;
#pragma unroll
  for (int it = 0; it < 16; it++) p += Wih[(size_t)o * 1024 + lane + it * 64] * b_lin[lane + it * 64];
#pragma unroll
  for (int m = 1; m < 64; m <<= 1) p += __shfl_xor(p, m);
  if (lane == 0) {
    float s = b_ih[o] + b_hh[o];
    bc0[R] = s;
    bc1[R] = s + p;
  }
}

__global__ __launch_bounds__(256) void bn_kernel(float* __restrict__ out) {
  int t = blockIdx.x >> 2;
  int d = ((blockIdx.x & 3) << 8) + threadIdx.x;
  float* base = out + (size_t)t * (256 * 1024) + d;
  float s = 0.f, s2 = 0.f;
  for (int b = 0; b < 256; b++) {
    float v = base[b * 1024];
    s += v;
    s2 += v * v;
  }
  float mean = s * (1.f / 256.f);
  float var = fmaxf(s2 * (1.f / 256.f) - mean * mean, 0.f);
  float rstd = rsqrtf(var + 1e-5f);
  for (int b = 0; b < 256; b++) base[b * 1024] = (base[b * 1024] - mean) * rstd;
}

extern "C" void kernel_launch(void* const* d_in, const int* in_sizes, int n_in,
                              void* d_out, int out_size, void* d_ws, size_t ws_size,
                              hipStream_t stream) {
  const float* inputs = (const float*)d_in[0];
  const float* W_ih = (const float*)d_in[1];
  const float* W_hh = (const float*)d_in[2];
  const float* b_ih = (const float*)d_in[3];
  const float* b_hh = (const float*)d_in[4];
  const float* W_lin = (const float*)d_in[5];
  const float* b_lin = (const float*)d_in[6];
  const float* h0 = (const float*)d_in[7];
  const float* c0 = (const float*)d_in[8];
  float* out = (float*)d_out;

  char* ws = (char*)d_ws;
  float* bc0 = (float*)(ws + 0);             // 16,384
  float* bc1 = (float*)(ws + 16384);         // 16,384
  float* cbuf = (float*)(ws + 32768);        // 1,048,576
  u16* Wlin_hi = (u16*)(ws + 1081344);       // 2,097,152
  u16* Beff_hi = (u16*)(ws + 3178496);       // 8,388,608
  u16* Beff_lo = (u16*)(ws + 11567104);      // 8,388,608
  u16* xhi = (u16*)(ws + 19955712);          // 524,288
  u16* xlo = (u16*)(ws + 20480000);          // 524,288
  u16* h0hi = (u16*)(ws + 21004288);         // 524,288
  u16* h0lo = (u16*)(ws + 21528576);         // 524,288
  u16* Hlo0 = (u16*)(ws + 22052864);         // 524,288
  u16* Hlo1 = (u16*)(ws + 22577152);         // 524,288
  u16* Hhi = (u16*)(ws + 23101440);          // 67,108,864 (128 slabs of 512KB)
  // transients aliased inside Hhi (dead after prep / step 0; first alias = slab 4,
  // first overwritten by step kernel t=4 which runs strictly later):
  u16* Whh_hi = (u16*)(ws + 23101440 + 2097152);    // slabs 4..19
  u16* Whh_lo = (u16*)(ws + 23101440 + 10485760);   // slabs 20..35
  u16* Wih_hi = (u16*)(ws + 23101440 + 18874368);   // slabs 36..51
  u16* Wih_lo = (u16*)(ws + 23101440 + 27262976);   // slabs 52..67
  u16* Wlt_hi = (u16*)(ws + 23101440 + 35651584);   // slabs 68..71
  u16* Wlt_lo = (u16*)(ws + 23101440 + 37748736);   // slabs 72..75
  float* Wc_f32 = (float*)(ws + 23101440 + 39845888);  // slabs 76..107

  prep_split<true, true><<<2048, 256, 0, stream>>>(W_ih, Wih_hi, Wih_lo);
  prep_split<true, true><<<2048, 256, 0, stream>>>(W_hh, Whh_hi, Whh_lo);
  prep_split<false, false><<<512, 256, 0, stream>>>(W_lin, Wlin_hi, nullptr);
  prep_wlt<<<512, 256, 0, stream>>>(W_lin, Wlt_hi, Wlt_lo);
  prep_a0<<<256, 256, 0, stream>>>(inputs, h0, c0, xhi, xlo, h0hi, h0lo, cbuf);
  prep_bias<<<1024, 256, 0, stream>>>(W_ih, b_ih, b_hh, b_lin, bc0, bc1);

  // W_c = W_ih @ W_lin (bf16x3), rows interleaved. M=4096, N=1024, K=1024.
  gemmk<64, 64, 16, 0, 0, 0, 16><<<1024, 256, 0, stream>>>(
      Wih_hi, Wih_lo, nullptr, nullptr, Wlt_hi, Wlt_lo, nullptr, nullptr,
      nullptr, nullptr, nullptr, nullptr, Wc_f32);
  prep_beff<<<2048, 256, 0, stream>>>(Wc_f32, W_hh, Beff_hi, Beff_lo);

  // step 0: gates from (x0,h0): two K-phases (x @ Wih, h @ Whh), K=2048 total.
  gemmk<64, 64, 32, 1, 1, 1, 0><<<256, 256, 0, stream>>>(
      xhi, xlo, h0hi, h0lo, Wih_hi, Wih_lo, Whh_hi, Whh_lo,
      bc0, cbuf, Hhi, Hlo0, nullptr);
  // steps 1..127: gates = h_{t-1} @ Beff^T (bf16x3 joint), K=1024.
  for (int t = 1; t < 128; t++) {
    gemmk<64, 64, 16, 0, 1, 1, 0><<<256, 256, 0, stream>>>(
        Hhi + (size_t)(t - 1) * SLABH, ((t - 1) & 1) ? Hlo1 : Hlo0, nullptr, nullptr,
        Beff_hi, Beff_lo, nullptr, nullptr,
        bc1, cbuf, Hhi + (size_t)t * SLABH, (t & 1) ? Hlo1 : Hlo0, nullptr);
  }

  // ys = Hs_hi @ W_lin_hi^T + b_lin (plain bf16). M=32768, N=1024, K=1024.
  gemmk<128, 128, 16, 2, 2, 2, 0><<<2048, 256, 0, stream>>>(
      Hhi, nullptr, nullptr, nullptr, Wlin_hi, nullptr, nullptr, nullptr,
      b_lin, nullptr, nullptr, nullptr, out);
  bn_kernel<<<512, 256, 0, stream>>>(out);
}